// Round 4
// baseline (466.545 us; speedup 1.0000x reference)
//
#include <hip/hip_runtime.h>
#include <hip/hip_bf16.h>

#define FDIM 128

typedef __attribute__((ext_vector_type(8))) short short8;
typedef __attribute__((ext_vector_type(4))) float f32x4;
typedef __attribute__((ext_vector_type(4))) float floatx4;
typedef __attribute__((ext_vector_type(4))) unsigned int uintx4;

__device__ inline float bflo(unsigned u) { return __uint_as_float(u << 16); }
__device__ inline float bfhi(unsigned u) { return __uint_as_float(u & 0xffff0000u); }
__device__ inline unsigned short f2bf(float f) {
    unsigned u = __float_as_uint(f);
    u += 0x7fffu + ((u >> 16) & 1u);   // RNE
    return (unsigned short)(u >> 16);
}
__device__ inline unsigned pack2(float a, float b) {
    return (unsigned)f2bf(a) | ((unsigned)f2bf(b) << 16);
}

// ---------------- degree count ----------------
__global__ __launch_bounds__(256) void deg_kernel(const int* __restrict__ dst, int* __restrict__ cnt, int E) {
    int e = blockIdx.x * 256 + threadIdx.x;
    if (e < E) atomicAdd(&cnt[dst[e]], 1);
}

// ---------------- scan phase A ----------------
__global__ __launch_bounds__(256) void scan_partial(const int* __restrict__ cnt, int* __restrict__ bsum, int n) {
    __shared__ int sdata[256];
    int b = blockIdx.x, t = threadIdx.x;
    int base = b * 1024;
    int s = 0;
    for (int i = 0; i < 4; i++) {
        int idx = base + t * 4 + i;
        if (idx < n) s += cnt[idx];
    }
    sdata[t] = s;
    __syncthreads();
    for (int off = 128; off > 0; off >>= 1) {
        if (t < off) sdata[t] += sdata[t + off];
        __syncthreads();
    }
    if (t == 0) bsum[b] = sdata[0];
}

// ---------------- scan phase B: exclusive scan of block sums (nb <= 256) ----------------
__global__ __launch_bounds__(256) void scan_sums(int* __restrict__ bsum, int nb) {
    __shared__ int sdata[256];
    int t = threadIdx.x;
    int v = (t < nb) ? bsum[t] : 0;
    sdata[t] = v;
    __syncthreads();
    for (int off = 1; off < 256; off <<= 1) {
        int u = (t >= off) ? sdata[t - off] : 0;
        __syncthreads();
        sdata[t] += u;
        __syncthreads();
    }
    if (t < nb) bsum[t] = sdata[t] - v;
}

// ---------------- scan phase C (+ fused dinv) ----------------
__global__ __launch_bounds__(256) void scan_final(const int* __restrict__ cnt, const int* __restrict__ bsum,
                                                  int* __restrict__ rowptr, float* __restrict__ dinv,
                                                  int n, int E) {
    __shared__ int sdata[256];
    int b = blockIdx.x, t = threadIdx.x;
    int base = b * 1024;
    int loc[4], vv[4];
    int s = 0;
    for (int i = 0; i < 4; i++) {
        int idx = base + t * 4 + i;
        int v = (idx < n) ? cnt[idx] : 0;
        vv[i] = v;
        loc[i] = s;
        s += v;
    }
    sdata[t] = s;
    __syncthreads();
    for (int off = 1; off < 256; off <<= 1) {
        int v = (t >= off) ? sdata[t - off] : 0;
        __syncthreads();
        sdata[t] += v;
        __syncthreads();
    }
    int texc = sdata[t] - s;
    int boff = bsum[b];
    for (int i = 0; i < 4; i++) {
        int idx = base + t * 4 + i;
        if (idx < n) {
            rowptr[idx] = boff + texc + loc[i];
            dinv[idx] = rsqrtf((float)(vv[i] + 1));
        }
    }
    if (b == 0 && t == 0) rowptr[n] = E;
}

// ---------------- CSR fill: consumes cnt via atomicSub (order within row is arbitrary anyway) ----------------
__global__ __launch_bounds__(256) void fill_kernel(const int* __restrict__ srcI, const int* __restrict__ dstI,
                                                   const int* __restrict__ rowptr, int* __restrict__ cnt,
                                                   int* __restrict__ col, int E) {
    int e = blockIdx.x * 256 + threadIdx.x;
    if (e < E) {
        int d = dstI[e];
        int old = atomicSub(&cnt[d], 1);
        col[rowptr[d] + old - 1] = srcI[e];
    }
}

// ---------------- weight prep: fp32 W[k][c] -> bf16, transposed [c][k] (contiguous) ----------------
__global__ __launch_bounds__(256) void wprep(const float* __restrict__ W1, const float* __restrict__ Wmu,
                                             const float* __restrict__ Wlv, unsigned short* __restrict__ out) {
    int t = blockIdx.x * 256 + threadIdx.x;    // 49152 total
    int m = t >> 14;
    int idx = t & 16383;
    const float* W = (m == 0) ? W1 : (m == 1) ? Wmu : Wlv;
    int k = idx >> 7, c = idx & 127;
    float v = W[idx];
    out[(m << 14) + (c << 7) + k] = f2bf(v);
}

// ---------------- convert: x_tilde = bf16(x * dinv[row]), 8 elems/thread ----------------
__global__ __launch_bounds__(256) void conv_scale(const float* __restrict__ X, const float* __restrict__ dinv,
                                                  uint4* __restrict__ Y, int nf8) {
    int i = blockIdx.x * 256 + threadIdx.x;
    if (i >= nf8) return;
    int row = i >> 4;                 // 16 uint4-slots per 128-elem row
    float d = dinv[row];
    const floatx4* X4 = (const floatx4*)X;
    floatx4 f0 = __builtin_nontemporal_load(&X4[i * 2]);
    floatx4 f1 = __builtin_nontemporal_load(&X4[i * 2 + 1]);
    uint4 o;
    o.x = pack2(f0.x * d, f0.y * d);
    o.y = pack2(f0.z * d, f0.w * d);
    o.z = pack2(f1.x * d, f1.y * d);
    o.w = pack2(f1.z * d, f1.w * d);
    Y[i] = o;
}

// ---------------- FUSED gather + MFMA GEMM + epilogue ----------------
// Per block: 64 output rows. Phase 1: 16 groups x 4 nodes gather (identical math/order to
// the previous standalone gather_agg) -> bf16 rows into XOR-swizzled LDS tile (16 KB).
// Phase 2: MFMA with A from LDS, B direct from prepped bf16 W[c][k] in global (L1/L2-hot).
// MODE 0: out = bf16(relu(GW+bA)*dinv)          (h~)
// MODE 1: mu/lv fp32 out; zt = bf16((eps*exp(.5lv)+mu)*dinv)
// MODE 2: out = fp32 sigmoid(GW+bA)             (recon)
template<int MODE>
__global__ __launch_bounds__(256) void fused_conv(const uint4* __restrict__ T, const int* __restrict__ rowptr,
                                                  const int* __restrict__ col, const float* __restrict__ dinv,
                                                  const unsigned short* __restrict__ WA,
                                                  const unsigned short* __restrict__ WB,
                                                  const float* __restrict__ biasA, const float* __restrict__ biasB,
                                                  const float* __restrict__ eps,
                                                  float* __restrict__ muO, float* __restrict__ lvO,
                                                  void* __restrict__ outp, int n) {
    __shared__ uint4 Gs[64 * 16];   // 64 rows x 16 slots(16B), slot XOR-swizzled by (row&7)
    int t = threadIdx.x;
    int g = t >> 4, lane16 = t & 15;
    int base = blockIdx.x * 64;

    // ---- phase 1: gather 4 nodes per 16-lane group ----
    for (int j = 0; j < 4; j++) {
        int r = g * 4 + j;          // LDS-local row
        int node = base + r;
        float acc[8];
        if (node < n) {
            size_t ridx = (size_t)node * 16 + lane16;
            uint4 v = T[ridx];      // self-loop
            acc[0] = bflo(v.x); acc[1] = bfhi(v.x); acc[2] = bflo(v.y); acc[3] = bfhi(v.y);
            acc[4] = bflo(v.z); acc[5] = bfhi(v.z); acc[6] = bflo(v.w); acc[7] = bfhi(v.w);
            auto add8 = [&](uint4 w) {
                acc[0] += bflo(w.x); acc[1] += bfhi(w.x); acc[2] += bflo(w.y); acc[3] += bfhi(w.y);
                acc[4] += bflo(w.z); acc[5] += bfhi(w.z); acc[6] += bflo(w.w); acc[7] += bfhi(w.w);
            };
            int rp0 = rowptr[node], rp1 = rowptr[node + 1];
            for (int eb = rp0; eb < rp1; eb += 16) {
                int e = eb + lane16;
                int myc = (e < rp1) ? col[e] : 0;
                int m = rp1 - eb; if (m > 16) m = 16;
                int i = 0;
                for (; i + 8 <= m; i += 8) {
                    int s0 = __shfl(myc, i, 16);
                    int s1 = __shfl(myc, i + 1, 16);
                    int s2 = __shfl(myc, i + 2, 16);
                    int s3 = __shfl(myc, i + 3, 16);
                    int s4 = __shfl(myc, i + 4, 16);
                    int s5 = __shfl(myc, i + 5, 16);
                    int s6 = __shfl(myc, i + 6, 16);
                    int s7 = __shfl(myc, i + 7, 16);
                    uint4 v0 = T[(size_t)s0 * 16 + lane16];
                    uint4 v1 = T[(size_t)s1 * 16 + lane16];
                    uint4 v2 = T[(size_t)s2 * 16 + lane16];
                    uint4 v3 = T[(size_t)s3 * 16 + lane16];
                    uint4 v4 = T[(size_t)s4 * 16 + lane16];
                    uint4 v5 = T[(size_t)s5 * 16 + lane16];
                    uint4 v6 = T[(size_t)s6 * 16 + lane16];
                    uint4 v7 = T[(size_t)s7 * 16 + lane16];
                    add8(v0); add8(v1); add8(v2); add8(v3);
                    add8(v4); add8(v5); add8(v6); add8(v7);
                }
                for (; i + 4 <= m; i += 4) {
                    int s0 = __shfl(myc, i, 16);
                    int s1 = __shfl(myc, i + 1, 16);
                    int s2 = __shfl(myc, i + 2, 16);
                    int s3 = __shfl(myc, i + 3, 16);
                    uint4 v0 = T[(size_t)s0 * 16 + lane16];
                    uint4 v1 = T[(size_t)s1 * 16 + lane16];
                    uint4 v2 = T[(size_t)s2 * 16 + lane16];
                    uint4 v3 = T[(size_t)s3 * 16 + lane16];
                    add8(v0); add8(v1); add8(v2); add8(v3);
                }
                for (; i < m; i++) {
                    int s = __shfl(myc, i, 16);
                    add8(T[(size_t)s * 16 + lane16]);
                }
            }
            float dj = dinv[node];
            #pragma unroll
            for (int q = 0; q < 8; q++) acc[q] *= dj;
        } else {
            #pragma unroll
            for (int q = 0; q < 8; q++) acc[q] = 0.f;
        }
        uint4 o;
        o.x = pack2(acc[0], acc[1]);
        o.y = pack2(acc[2], acc[3]);
        o.z = pack2(acc[4], acc[5]);
        o.w = pack2(acc[6], acc[7]);
        Gs[r * 16 + (lane16 ^ (r & 7))] = o;
    }
    __syncthreads();

    // ---- phase 2: MFMA ----
    int wave = t >> 6, lane = t & 63;
    int quad = lane >> 4, mrow = lane & 15;
    int row0 = base + wave * 16;
    const short8* Gp = (const short8*)Gs;
    const short8* WA8 = (const short8*)WA;
    const short8* WB8 = (const short8*)WB;

    if (MODE == 1) {
        f32x4 am[8], al[8];
        #pragma unroll
        for (int i = 0; i < 8; i++) { am[i] = (f32x4){0.f,0.f,0.f,0.f}; al[i] = (f32x4){0.f,0.f,0.f,0.f}; }
        #pragma unroll
        for (int kb = 0; kb < 4; kb++) {
            int slot = (kb * 4 + quad) ^ (mrow & 7);
            short8 a = Gp[(wave * 16 + mrow) * 16 + slot];
            #pragma unroll
            for (int tile = 0; tile < 8; tile++) {
                int colc = tile * 16 + mrow;
                short8 b0 = WA8[colc * 16 + kb * 4 + quad];
                am[tile] = __builtin_amdgcn_mfma_f32_16x16x32_bf16(a, b0, am[tile], 0, 0, 0);
                short8 b1 = WB8[colc * 16 + kb * 4 + quad];
                al[tile] = __builtin_amdgcn_mfma_f32_16x16x32_bf16(a, b1, al[tile], 0, 0, 0);
            }
        }
        unsigned short* zt = (unsigned short*)outp;
        #pragma unroll
        for (int r = 0; r < 4; r++) {
            int rowg = row0 + quad * 4 + r;
            if (rowg >= n) continue;
            float dj = dinv[rowg];
            #pragma unroll
            for (int tile = 0; tile < 8; tile++) {
                int c = tile * 16 + mrow;
                size_t o = (size_t)rowg * FDIM + c;
                float m = am[tile][r] + biasA[c];
                float l = al[tile][r] + biasB[c];
                __builtin_nontemporal_store(m, &muO[o]);
                __builtin_nontemporal_store(l, &lvO[o]);
                float ev = __builtin_nontemporal_load(&eps[o]);
                float z = ev * expf(0.5f * l) + m;
                zt[o] = f2bf(z * dj);
            }
        }
    } else {
        f32x4 acc[8];
        #pragma unroll
        for (int i = 0; i < 8; i++) acc[i] = (f32x4){0.f, 0.f, 0.f, 0.f};
        #pragma unroll
        for (int kb = 0; kb < 4; kb++) {
            int slot = (kb * 4 + quad) ^ (mrow & 7);
            short8 a = Gp[(wave * 16 + mrow) * 16 + slot];
            #pragma unroll
            for (int tile = 0; tile < 8; tile++) {
                int colc = tile * 16 + mrow;
                short8 b = WA8[colc * 16 + kb * 4 + quad];
                acc[tile] = __builtin_amdgcn_mfma_f32_16x16x32_bf16(a, b, acc[tile], 0, 0, 0);
            }
        }
        #pragma unroll
        for (int r = 0; r < 4; r++) {
            int rowg = row0 + quad * 4 + r;
            if (rowg >= n) continue;
            if (MODE == 0) {
                float dj = dinv[rowg];
                unsigned short* Y = (unsigned short*)outp;
                #pragma unroll
                for (int tile = 0; tile < 8; tile++) {
                    int c = tile * 16 + mrow;
                    float v = fmaxf(acc[tile][r] + biasA[c], 0.f) * dj;
                    Y[(size_t)rowg * FDIM + c] = f2bf(v);
                }
            } else {
                float* Y = (float*)outp;
                #pragma unroll
                for (int tile = 0; tile < 8; tile++) {
                    int c = tile * 16 + mrow;
                    float v = acc[tile][r] + biasA[c];
                    __builtin_nontemporal_store(1.f / (1.f + expf(-v)), &Y[(size_t)rowg * FDIM + c]);
                }
            }
        }
    }
}

extern "C" void kernel_launch(void* const* d_in, const int* in_sizes, int n_in,
                              void* d_out, int out_size, void* d_ws, size_t ws_size,
                              hipStream_t stream) {
    const int F = FDIM;
    const int N = in_sizes[0] / F;
    const int E = in_sizes[1] / 2;

    const float* x   = (const float*)d_in[0];
    const int*   ei  = (const int*)d_in[1];
    const int*   srcI = ei;
    const int*   dstI = ei + E;
    const float* eps = (const float*)d_in[2];
    const float* W1  = (const float*)d_in[3];
    const float* b1  = (const float*)d_in[4];
    const float* Wmu = (const float*)d_in[5];
    const float* bmu = (const float*)d_in[6];
    const float* Wlv = (const float*)d_in[7];
    const float* blv = (const float*)d_in[8];

    float* recon = (float*)d_out;
    size_t NF = (size_t)N * F;
    float* muO = recon + NF;
    float* lvO = recon + 2 * NF;

    size_t off = 0;
    auto alloc = [&](size_t bytes) -> void* {
        void* p = (char*)d_ws + off;
        off += (bytes + 255) & ~(size_t)255;
        return p;
    };
    int*   cnt    = (int*)alloc((size_t)N * 4);
    int*   rowptr = (int*)alloc((size_t)(N + 1) * 4);
    int*   bsum   = (int*)alloc(4096);
    int*   col    = (int*)alloc((size_t)E * 4);
    float* dinv   = (float*)alloc((size_t)N * 4);
    unsigned short* WtP = (unsigned short*)alloc((size_t)3 * 16384 * 2);  // prepped W1,Wmu,Wlv
    unsigned short* bufA = (unsigned short*)alloc(NF * 2);  // x~, then z~
    unsigned short* bufB = (unsigned short*)alloc(NF * 2);  // h~

    hipMemsetAsync(cnt, 0, (size_t)N * 4, stream);

    int eb = (E + 255) / 256;
    int NB = (N + 1023) / 1024;
    deg_kernel<<<eb, 256, 0, stream>>>(dstI, cnt, E);
    scan_partial<<<NB, 256, 0, stream>>>(cnt, bsum, N);
    scan_sums<<<1, 256, 0, stream>>>(bsum, NB);
    scan_final<<<NB, 256, 0, stream>>>(cnt, bsum, rowptr, dinv, N, E);
    fill_kernel<<<eb, 256, 0, stream>>>(srcI, dstI, rowptr, cnt, col, E);
    wprep<<<192, 256, 0, stream>>>(W1, Wmu, Wlv, WtP);

    int nf8 = (int)(NF / 8);
    int cb = (nf8 + 255) / 256;
    int gb = (N + 63) / 64;

    const unsigned short* W1P  = WtP;
    const unsigned short* WmuP = WtP + 16384;
    const unsigned short* WlvP = WtP + 32768;

    // x~ = bf16(x * dinv)
    conv_scale<<<cb, 256, 0, stream>>>(x, dinv, (uint4*)bufA, nf8);
    // h~ = relu(Agg(x~) @ W1 + b1) * dinv          (bufA -> bufB)
    fused_conv<0><<<gb, 256, 0, stream>>>((const uint4*)bufA, rowptr, col, dinv,
                                          W1P, nullptr, b1, nullptr,
                                          nullptr, nullptr, nullptr, bufB, N);
    // mu, logvar, z~ = f(Agg(h~))                  (bufB -> bufA, muO, lvO)
    fused_conv<1><<<gb, 256, 0, stream>>>((const uint4*)bufB, rowptr, col, dinv,
                                          WmuP, WlvP, bmu, blv,
                                          eps, muO, lvO, bufA, N);
    // recon = sigmoid(Agg(z~) @ W1 + b1)           (bufA -> recon)
    fused_conv<2><<<gb, 256, 0, stream>>>((const uint4*)bufA, rowptr, col, dinv,
                                          W1P, nullptr, b1, nullptr,
                                          nullptr, nullptr, nullptr, recon, N);
}

// Round 5
// 427.679 us; speedup vs baseline: 1.0909x; 1.0909x over previous
//
#include <hip/hip_runtime.h>
#include <hip/hip_bf16.h>

#define FDIM 128

typedef __attribute__((ext_vector_type(8))) short short8;
typedef __attribute__((ext_vector_type(4))) float f32x4;
typedef __attribute__((ext_vector_type(4))) float floatx4;

__device__ inline float bflo(unsigned u) { return __uint_as_float(u << 16); }
__device__ inline float bfhi(unsigned u) { return __uint_as_float(u & 0xffff0000u); }
__device__ inline unsigned short f2bf(float f) {
    unsigned u = __float_as_uint(f);
    u += 0x7fffu + ((u >> 16) & 1u);   // RNE
    return (unsigned short)(u >> 16);
}
__device__ inline unsigned pack2(float a, float b) {
    return (unsigned)f2bf(a) | ((unsigned)f2bf(b) << 16);
}

// ---------------- degree count ----------------
__global__ __launch_bounds__(256) void deg_kernel(const int* __restrict__ dst, int* __restrict__ cnt, int E) {
    int e = blockIdx.x * 256 + threadIdx.x;
    if (e < E) atomicAdd(&cnt[dst[e]], 1);
}

// ---------------- scan phase A ----------------
__global__ __launch_bounds__(256) void scan_partial(const int* __restrict__ cnt, int* __restrict__ bsum, int n) {
    __shared__ int sdata[256];
    int b = blockIdx.x, t = threadIdx.x;
    int base = b * 1024;
    int s = 0;
    for (int i = 0; i < 4; i++) {
        int idx = base + t * 4 + i;
        if (idx < n) s += cnt[idx];
    }
    sdata[t] = s;
    __syncthreads();
    for (int off = 128; off > 0; off >>= 1) {
        if (t < off) sdata[t] += sdata[t + off];
        __syncthreads();
    }
    if (t == 0) bsum[b] = sdata[0];
}

// ---------------- scan phase B: exclusive scan of block sums (nb <= 256) ----------------
__global__ __launch_bounds__(256) void scan_sums(int* __restrict__ bsum, int nb) {
    __shared__ int sdata[256];
    int t = threadIdx.x;
    int v = (t < nb) ? bsum[t] : 0;
    sdata[t] = v;
    __syncthreads();
    for (int off = 1; off < 256; off <<= 1) {
        int u = (t >= off) ? sdata[t - off] : 0;
        __syncthreads();
        sdata[t] += u;
        __syncthreads();
    }
    if (t < nb) bsum[t] = sdata[t] - v;
}

// ---------------- scan phase C (+ fused dinv) ----------------
__global__ __launch_bounds__(256) void scan_final(const int* __restrict__ cnt, const int* __restrict__ bsum,
                                                  int* __restrict__ rowptr, float* __restrict__ dinv,
                                                  int n, int E) {
    __shared__ int sdata[256];
    int b = blockIdx.x, t = threadIdx.x;
    int base = b * 1024;
    int loc[4], vv[4];
    int s = 0;
    for (int i = 0; i < 4; i++) {
        int idx = base + t * 4 + i;
        int v = (idx < n) ? cnt[idx] : 0;
        vv[i] = v;
        loc[i] = s;
        s += v;
    }
    sdata[t] = s;
    __syncthreads();
    for (int off = 1; off < 256; off <<= 1) {
        int v = (t >= off) ? sdata[t - off] : 0;
        __syncthreads();
        sdata[t] += v;
        __syncthreads();
    }
    int texc = sdata[t] - s;
    int boff = bsum[b];
    for (int i = 0; i < 4; i++) {
        int idx = base + t * 4 + i;
        if (idx < n) {
            rowptr[idx] = boff + texc + loc[i];
            dinv[idx] = rsqrtf((float)(vv[i] + 1));
        }
    }
    if (b == 0 && t == 0) rowptr[n] = E;
}

// ---------------- CSR fill: consumes cnt via atomicSub (order within row is arbitrary anyway) ----------------
__global__ __launch_bounds__(256) void fill_kernel(const int* __restrict__ srcI, const int* __restrict__ dstI,
                                                   const int* __restrict__ rowptr, int* __restrict__ cnt,
                                                   int* __restrict__ col, int E) {
    int e = blockIdx.x * 256 + threadIdx.x;
    if (e < E) {
        int d = dstI[e];
        int old = atomicSub(&cnt[d], 1);
        col[rowptr[d] + old - 1] = srcI[e];
    }
}

// ---------------- weight prep: fp32 W[k][c] -> bf16, transposed [c][k] (contiguous) ----------------
__global__ __launch_bounds__(256) void wprep(const float* __restrict__ W1, const float* __restrict__ Wmu,
                                             const float* __restrict__ Wlv, unsigned short* __restrict__ out) {
    int t = blockIdx.x * 256 + threadIdx.x;    // 49152 total
    int m = t >> 14;
    int idx = t & 16383;
    const float* W = (m == 0) ? W1 : (m == 1) ? Wmu : Wlv;
    int k = idx >> 7, c = idx & 127;
    float v = W[idx];
    out[(m << 14) + (c << 7) + k] = f2bf(v);
}

// ---------------- convert: x_tilde = bf16(x * dinv[row]), 8 elems/thread ----------------
__global__ __launch_bounds__(256) void conv_scale(const float* __restrict__ X, const float* __restrict__ dinv,
                                                  uint4* __restrict__ Y, int nf8) {
    int i = blockIdx.x * 256 + threadIdx.x;
    if (i >= nf8) return;
    int row = i >> 4;                 // 16 uint4-slots per 128-elem row
    float d = dinv[row];
    const floatx4* X4 = (const floatx4*)X;
    floatx4 f0 = __builtin_nontemporal_load(&X4[i * 2]);
    floatx4 f1 = __builtin_nontemporal_load(&X4[i * 2 + 1]);
    uint4 o;
    o.x = pack2(f0.x * d, f0.y * d);
    o.y = pack2(f0.z * d, f0.w * d);
    o.z = pack2(f1.x * d, f1.y * d);
    o.w = pack2(f1.z * d, f1.w * d);
    Y[i] = o;
}

// ---------------- FUSED gather + MFMA GEMM + epilogue (16 nodes/block) ----------------
// Phase 1: 16 groups x 1 node each (identical structure to the fast standalone gather)
//          -> bf16 rows into XOR-swizzled 4 KB LDS tile.
// Phase 2: 16-row GEMM; each of 4 waves computes 2 column-tiles; B direct from prepped
//          bf16 W[c][k] in global (L1/L2-hot, 32 KB).
// MODE 0: out = bf16(relu(GW+bA)*dinv)          (h~)
// MODE 1: mu/lv fp32 out; zt = bf16((eps*exp(.5lv)+mu)*dinv)
// MODE 2: out = fp32 sigmoid(GW+bA)             (recon)
template<int MODE>
__global__ __launch_bounds__(256) void fused_conv(const uint4* __restrict__ T, const int* __restrict__ rowptr,
                                                  const int* __restrict__ col, const float* __restrict__ dinv,
                                                  const unsigned short* __restrict__ WA,
                                                  const unsigned short* __restrict__ WB,
                                                  const float* __restrict__ biasA, const float* __restrict__ biasB,
                                                  const float* __restrict__ eps,
                                                  float* __restrict__ muO, float* __restrict__ lvO,
                                                  void* __restrict__ outp, int n) {
    __shared__ uint4 Gs[16 * 16];   // 16 rows x 16 slots(16B), slot XOR-swizzled by (row&7)
    int t = threadIdx.x;
    int g = t >> 4, lane16 = t & 15;
    int base = blockIdx.x * 16;
    int node = base + g;

    // ---- phase 1: gather, one node per 16-lane group ----
    {
        float acc[8];
        if (node < n) {
            size_t ridx = (size_t)node * 16 + lane16;
            uint4 v = T[ridx];      // self-loop
            acc[0] = bflo(v.x); acc[1] = bfhi(v.x); acc[2] = bflo(v.y); acc[3] = bfhi(v.y);
            acc[4] = bflo(v.z); acc[5] = bfhi(v.z); acc[6] = bflo(v.w); acc[7] = bfhi(v.w);
            auto add8 = [&](uint4 w) {
                acc[0] += bflo(w.x); acc[1] += bfhi(w.x); acc[2] += bflo(w.y); acc[3] += bfhi(w.y);
                acc[4] += bflo(w.z); acc[5] += bfhi(w.z); acc[6] += bflo(w.w); acc[7] += bfhi(w.w);
            };
            int rp0 = rowptr[node], rp1 = rowptr[node + 1];
            for (int eb = rp0; eb < rp1; eb += 16) {
                int e = eb + lane16;
                int myc = (e < rp1) ? col[e] : 0;
                int m = rp1 - eb; if (m > 16) m = 16;
                int i = 0;
                for (; i + 8 <= m; i += 8) {
                    int s0 = __shfl(myc, i, 16);
                    int s1 = __shfl(myc, i + 1, 16);
                    int s2 = __shfl(myc, i + 2, 16);
                    int s3 = __shfl(myc, i + 3, 16);
                    int s4 = __shfl(myc, i + 4, 16);
                    int s5 = __shfl(myc, i + 5, 16);
                    int s6 = __shfl(myc, i + 6, 16);
                    int s7 = __shfl(myc, i + 7, 16);
                    uint4 v0 = T[(size_t)s0 * 16 + lane16];
                    uint4 v1 = T[(size_t)s1 * 16 + lane16];
                    uint4 v2 = T[(size_t)s2 * 16 + lane16];
                    uint4 v3 = T[(size_t)s3 * 16 + lane16];
                    uint4 v4 = T[(size_t)s4 * 16 + lane16];
                    uint4 v5 = T[(size_t)s5 * 16 + lane16];
                    uint4 v6 = T[(size_t)s6 * 16 + lane16];
                    uint4 v7 = T[(size_t)s7 * 16 + lane16];
                    add8(v0); add8(v1); add8(v2); add8(v3);
                    add8(v4); add8(v5); add8(v6); add8(v7);
                }
                for (; i + 4 <= m; i += 4) {
                    int s0 = __shfl(myc, i, 16);
                    int s1 = __shfl(myc, i + 1, 16);
                    int s2 = __shfl(myc, i + 2, 16);
                    int s3 = __shfl(myc, i + 3, 16);
                    uint4 v0 = T[(size_t)s0 * 16 + lane16];
                    uint4 v1 = T[(size_t)s1 * 16 + lane16];
                    uint4 v2 = T[(size_t)s2 * 16 + lane16];
                    uint4 v3 = T[(size_t)s3 * 16 + lane16];
                    add8(v0); add8(v1); add8(v2); add8(v3);
                }
                for (; i < m; i++) {
                    int s = __shfl(myc, i, 16);
                    add8(T[(size_t)s * 16 + lane16]);
                }
            }
            float dj = dinv[node];
            #pragma unroll
            for (int q = 0; q < 8; q++) acc[q] *= dj;
        } else {
            #pragma unroll
            for (int q = 0; q < 8; q++) acc[q] = 0.f;
        }
        uint4 o;
        o.x = pack2(acc[0], acc[1]);
        o.y = pack2(acc[2], acc[3]);
        o.z = pack2(acc[4], acc[5]);
        o.w = pack2(acc[6], acc[7]);
        Gs[g * 16 + (lane16 ^ (g & 7))] = o;
    }
    __syncthreads();

    // ---- phase 2: MFMA, 16 rows x 128 cols; wave w owns column-tiles {2w, 2w+1} ----
    int wave = t >> 6, lane = t & 63;
    int quad = lane >> 4, mrow = lane & 15;
    const short8* Gp = (const short8*)Gs;
    const short8* WA8 = (const short8*)WA;
    const short8* WB8 = (const short8*)WB;

    if (MODE == 1) {
        f32x4 am[2], al[2];
        #pragma unroll
        for (int i = 0; i < 2; i++) { am[i] = (f32x4){0.f,0.f,0.f,0.f}; al[i] = (f32x4){0.f,0.f,0.f,0.f}; }
        #pragma unroll
        for (int kb = 0; kb < 4; kb++) {
            int slot = (kb * 4 + quad) ^ (mrow & 7);
            short8 a = Gp[mrow * 16 + slot];
            #pragma unroll
            for (int tt = 0; tt < 2; tt++) {
                int colc = (wave * 2 + tt) * 16 + mrow;
                short8 b0 = WA8[colc * 16 + kb * 4 + quad];
                am[tt] = __builtin_amdgcn_mfma_f32_16x16x32_bf16(a, b0, am[tt], 0, 0, 0);
                short8 b1 = WB8[colc * 16 + kb * 4 + quad];
                al[tt] = __builtin_amdgcn_mfma_f32_16x16x32_bf16(a, b1, al[tt], 0, 0, 0);
            }
        }
        unsigned short* zt = (unsigned short*)outp;
        #pragma unroll
        for (int r = 0; r < 4; r++) {
            int rowg = base + quad * 4 + r;
            if (rowg >= n) continue;
            float dj = dinv[rowg];
            #pragma unroll
            for (int tt = 0; tt < 2; tt++) {
                int c = (wave * 2 + tt) * 16 + mrow;
                size_t o = (size_t)rowg * FDIM + c;
                float m = am[tt][r] + biasA[c];
                float l = al[tt][r] + biasB[c];
                __builtin_nontemporal_store(m, &muO[o]);
                __builtin_nontemporal_store(l, &lvO[o]);
                float ev = __builtin_nontemporal_load(&eps[o]);
                float z = ev * expf(0.5f * l) + m;
                zt[o] = f2bf(z * dj);
            }
        }
    } else {
        f32x4 acc[2];
        #pragma unroll
        for (int i = 0; i < 2; i++) acc[i] = (f32x4){0.f, 0.f, 0.f, 0.f};
        #pragma unroll
        for (int kb = 0; kb < 4; kb++) {
            int slot = (kb * 4 + quad) ^ (mrow & 7);
            short8 a = Gp[mrow * 16 + slot];
            #pragma unroll
            for (int tt = 0; tt < 2; tt++) {
                int colc = (wave * 2 + tt) * 16 + mrow;
                short8 b = WA8[colc * 16 + kb * 4 + quad];
                acc[tt] = __builtin_amdgcn_mfma_f32_16x16x32_bf16(a, b, acc[tt], 0, 0, 0);
            }
        }
        #pragma unroll
        for (int r = 0; r < 4; r++) {
            int rowg = base + quad * 4 + r;
            if (rowg >= n) continue;
            if (MODE == 0) {
                float dj = dinv[rowg];
                unsigned short* Y = (unsigned short*)outp;
                #pragma unroll
                for (int tt = 0; tt < 2; tt++) {
                    int c = (wave * 2 + tt) * 16 + mrow;
                    float v = fmaxf(acc[tt][r] + biasA[c], 0.f) * dj;
                    Y[(size_t)rowg * FDIM + c] = f2bf(v);
                }
            } else {
                float* Y = (float*)outp;
                #pragma unroll
                for (int tt = 0; tt < 2; tt++) {
                    int c = (wave * 2 + tt) * 16 + mrow;
                    float v = acc[tt][r] + biasA[c];
                    __builtin_nontemporal_store(1.f / (1.f + expf(-v)), &Y[(size_t)rowg * FDIM + c]);
                }
            }
        }
    }
}

extern "C" void kernel_launch(void* const* d_in, const int* in_sizes, int n_in,
                              void* d_out, int out_size, void* d_ws, size_t ws_size,
                              hipStream_t stream) {
    const int F = FDIM;
    const int N = in_sizes[0] / F;
    const int E = in_sizes[1] / 2;

    const float* x   = (const float*)d_in[0];
    const int*   ei  = (const int*)d_in[1];
    const int*   srcI = ei;
    const int*   dstI = ei + E;
    const float* eps = (const float*)d_in[2];
    const float* W1  = (const float*)d_in[3];
    const float* b1  = (const float*)d_in[4];
    const float* Wmu = (const float*)d_in[5];
    const float* bmu = (const float*)d_in[6];
    const float* Wlv = (const float*)d_in[7];
    const float* blv = (const float*)d_in[8];

    float* recon = (float*)d_out;
    size_t NF = (size_t)N * F;
    float* muO = recon + NF;
    float* lvO = recon + 2 * NF;

    size_t off = 0;
    auto alloc = [&](size_t bytes) -> void* {
        void* p = (char*)d_ws + off;
        off += (bytes + 255) & ~(size_t)255;
        return p;
    };
    int*   cnt    = (int*)alloc((size_t)N * 4);
    int*   rowptr = (int*)alloc((size_t)(N + 1) * 4);
    int*   bsum   = (int*)alloc(4096);
    int*   col    = (int*)alloc((size_t)E * 4);
    float* dinv   = (float*)alloc((size_t)N * 4);
    unsigned short* WtP = (unsigned short*)alloc((size_t)3 * 16384 * 2);  // prepped W1,Wmu,Wlv
    unsigned short* bufA = (unsigned short*)alloc(NF * 2);  // x~, then z~
    unsigned short* bufB = (unsigned short*)alloc(NF * 2);  // h~

    hipMemsetAsync(cnt, 0, (size_t)N * 4, stream);

    int eb = (E + 255) / 256;
    int NB = (N + 1023) / 1024;
    deg_kernel<<<eb, 256, 0, stream>>>(dstI, cnt, E);
    scan_partial<<<NB, 256, 0, stream>>>(cnt, bsum, N);
    scan_sums<<<1, 256, 0, stream>>>(bsum, NB);
    scan_final<<<NB, 256, 0, stream>>>(cnt, bsum, rowptr, dinv, N, E);
    fill_kernel<<<eb, 256, 0, stream>>>(srcI, dstI, rowptr, cnt, col, E);
    wprep<<<192, 256, 0, stream>>>(W1, Wmu, Wlv, WtP);

    int nf8 = (int)(NF / 8);
    int cb = (nf8 + 255) / 256;
    int gb = (N + 15) / 16;

    const unsigned short* W1P  = WtP;
    const unsigned short* WmuP = WtP + 16384;
    const unsigned short* WlvP = WtP + 32768;

    // x~ = bf16(x * dinv)
    conv_scale<<<cb, 256, 0, stream>>>(x, dinv, (uint4*)bufA, nf8);
    // h~ = relu(Agg(x~) @ W1 + b1) * dinv          (bufA -> bufB)
    fused_conv<0><<<gb, 256, 0, stream>>>((const uint4*)bufA, rowptr, col, dinv,
                                          W1P, nullptr, b1, nullptr,
                                          nullptr, nullptr, nullptr, bufB, N);
    // mu, logvar, z~ = f(Agg(h~))                  (bufB -> bufA, muO, lvO)
    fused_conv<1><<<gb, 256, 0, stream>>>((const uint4*)bufB, rowptr, col, dinv,
                                          WmuP, WlvP, bmu, blv,
                                          eps, muO, lvO, bufA, N);
    // recon = sigmoid(Agg(z~) @ W1 + b1)           (bufA -> recon)
    fused_conv<2><<<gb, 256, 0, stream>>>((const uint4*)bufA, rowptr, col, dinv,
                                          W1P, nullptr, b1, nullptr,
                                          nullptr, nullptr, nullptr, recon, N);
}